// Round 14
// baseline (399.492 us; speedup 1.0000x reference)
//
#include <hip/hip_runtime.h>
#include <hip/hip_bf16.h>
#include <stdint.h>

typedef __attribute__((ext_vector_type(4))) float f32x4;
typedef __attribute__((ext_vector_type(8))) short bf16x8;
typedef unsigned short u16;

#define T_TOK   2048
#define D_DIM   2048
#define DFF_DIM 1024
#define NEXP    8
#define TOPK    2
#define NROWS   (T_TOK * TOPK)   // 4096
#define BM      128
#define BK      64
#define MAX_MB  40
#define GRID_G  (16 * MAX_MB)    // 640 = 8 XCDs x 80

// ---- workspace layout (16.5 MB) ----
#define XB_OFF    65536
#define H_OFF     (XB_OFF + (size_t)T_TOK * D_DIM * 2)
#define X_T       ((size_t)T_TOK * D_DIM / 8)
#define PREPX_BLKS 512

#define PIN() asm volatile("" ::: "memory")
// barrier 1: LDS reads done; ALL vmem stays in flight
#define BAR_LGKM()                                                        \
    asm volatile("s_waitcnt lgkmcnt(0)" ::: "memory");                    \
    __builtin_amdgcn_s_barrier()
// barrier 2: drain glls (older) + ds_writes; keep 8 newest rb loads in flight
#define BAR_V8()                                                          \
    asm volatile("s_waitcnt vmcnt(8) lgkmcnt(0)" ::: "memory");           \
    __builtin_amdgcn_s_barrier()

__device__ __forceinline__ u16 f2bf(float f) {
    __hip_bfloat16 h = __float2bfloat16(f);
    return *reinterpret_cast<u16*>(&h);
}

__device__ __forceinline__ void cvt8_nt(const float* src, u16* dst) {
    f32x4 a = __builtin_nontemporal_load((const f32x4*)src);
    f32x4 b = __builtin_nontemporal_load(((const f32x4*)src) + 1);
    bf16x8 v;
#pragma unroll
    for (int j = 0; j < 4; ++j) { v[j] = (short)f2bf(a[j]); v[j + 4] = (short)f2bf(b[j]); }
    *(bf16x8*)dst = v;
}

__device__ __forceinline__ void gll16(const u16* gsrc, const u16* lds) {
    __builtin_amdgcn_global_load_lds(
        (const __attribute__((address_space(1))) uint32_t*)gsrc,
        (__attribute__((address_space(3))) uint32_t*)lds, 16, 0, 0);
}

// tile [128 rows][64 bf16=128B]; content XOR-swizzled by row
__device__ __forceinline__ bf16x8 lds_read8_swz(const u16* base, int row, int inner) {
    int off = row * 128 + (inner ^ ((row & 7) << 4));
    return *(const bf16x8*)((const char*)base + off);
}

__device__ __forceinline__ void route_body(const int* topk_ids, const float* topk_w,
                                           int* sched, int* row_token, float* row_w,
                                           int* cnt, int* off, int* cur) {
    const int tid = threadIdx.x;
    if (tid < NEXP) cnt[tid] = 0;
    __syncthreads();
    for (int p = tid; p < NROWS; p += blockDim.x)
        atomicAdd(&cnt[topk_ids[p]], 1);
    __syncthreads();
    if (tid == 0) {
        int acc = 0, mb = 0;
        for (int e = 0; e < NEXP; ++e) {
            off[e] = acc;
            int c = cnt[e];
            for (int m0 = 0; m0 < c; m0 += BM) {
                sched[1 + 3 * mb] = e;
                sched[2 + 3 * mb] = acc + m0;
                sched[3 + 3 * mb] = (c - m0 < BM) ? (c - m0) : BM;
                ++mb;
            }
            acc += c;
        }
        sched[0] = mb;
    }
    if (tid < NEXP) cur[tid] = 0;
    __syncthreads();
    for (int p = tid; p < NROWS; p += blockDim.x) {
        int e = topk_ids[p];
        int slot = off[e] + atomicAdd(&cur[e], 1);
        row_token[slot] = p / TOPK;
        row_w[slot]     = topk_w[p];
    }
}

// ---------------- prep_small: X -> bf16 (NT); zero d_out; route --------------
__global__ void prep_kernel(const float* __restrict__ X,
                            u16* __restrict__ Xb, float* __restrict__ out,
                            const int* __restrict__ topk_ids,
                            const float* __restrict__ topk_w,
                            int* __restrict__ sched, int* __restrict__ row_token,
                            float* __restrict__ row_w) {
    __shared__ int cnt[NEXP], off[NEXP], cur[NEXP];
    if (blockIdx.x == PREPX_BLKS) {
        route_body(topk_ids, topk_w, sched, row_token, row_w, cnt, off, cur);
        return;
    }
    const size_t stride = (size_t)PREPX_BLKS * 256;
    for (size_t t = (size_t)blockIdx.x * 256 + threadIdx.x; t < X_T; t += stride) {
        cvt8_nt(X + t * 8, Xb + t * 8);
        f32x4 z = (f32x4){0.f, 0.f, 0.f, 0.f};
        *(f32x4*)(out + t * 8) = z;
        *(f32x4*)(out + t * 8 + 4) = z;
    }
}

// XCD map: blocks sharing a B-tile (same e,n0; different m0) land on ONE XCD.
#define DECODE_BLOCK()                                                    \
    const int bid   = blockIdx.x;                                         \
    const int xcd   = bid & 7;                                            \
    const int local = bid >> 3;            /* 0..79 */                    \
    const int n0h   = local / MAX_MB;      /* 0..1  */                    \
    const int mb    = local - n0h * MAX_MB;                               \
    const int n0i   = xcd * 2 + n0h;       /* 0..15 */                    \
    if (mb >= sched[0]) return;                                           \
    const int e    = sched[1 + 3 * mb];                                   \
    const int m0   = sched[2 + 3 * mb];                                   \
    const int mlen = sched[3 + 3 * mb]

#define GLL_A(k0, dst)                                                    \
    _Pragma("unroll") for (int i = 0; i < 4; ++i)                         \
        gll16(asrc[i] + (k0), &(dst)[aoff[i]]);

#define LOAD_RB(rb, k0)                                                   \
    _Pragma("unroll") for (int i = 0; i < 4; ++i) {                       \
        rb[i][0] = *(const f32x4*)(bptr[i] + (k0));                       \
        rb[i][1] = *(const f32x4*)(bptr[i] + (k0) + 4);                   \
    }

#define CVT_WRITE(rb, dst)                                                \
    _Pragma("unroll") for (int i = 0; i < 4; ++i) {                       \
        bf16x8 vb;                                                        \
        _Pragma("unroll") for (int j = 0; j < 4; ++j) {                   \
            vb[j] = (short)f2bf(rb[i][0][j]);                             \
            vb[j + 4] = (short)f2bf(rb[i][1][j]);                         \
        }                                                                 \
        *(bf16x8*)((char*)(dst) + wroff[i]) = vb;                         \
    }

// ---------------- GEMM1: gathered Xb(gll) @ w1(f32, 2-deep reg pipe) ---------
__global__ __launch_bounds__(256, 3)
void gemm1_kernel(const u16* __restrict__ Xb, const float* __restrict__ w1,
                  const int* __restrict__ sched, const int* __restrict__ row_token,
                  u16* __restrict__ H) {
    __shared__ u16 lA[2][BM * BK];   // 32KB dbuf, gll (linear dest, pre-swz src)
    __shared__ u16 lB[BM * BK];      // 16KB, reg-staged f32->bf16 + swizzled

    DECODE_BLOCK();
    const int n0 = n0i * 64;

    const int tid  = threadIdx.x;
    const int lane = tid & 63;
    const int wave = tid >> 6;
    const int wm = wave >> 1, wn = wave & 1;
    const int lr = lane & 15, lk = lane >> 4;

    const u16* asrc[4];
    int aoff[4];
#pragma unroll
    for (int i = 0; i < 4; ++i) {
        int R = i * 32 + wave * 8 + (lane >> 3);
        int grow = m0 + R; if (grow > NROWS - 1) grow = NROWS - 1;
        int tok = row_token[grow];
        asrc[i] = Xb + (size_t)tok * D_DIM + (size_t)(((lane & 7) ^ (R & 7)) * 8);
        aoff[i] = i * 2048 + wave * 512;
    }
    const float* bptr[4];
    int wroff[4];
#pragma unroll
    for (int i = 0; i < 4; ++i) {
        int chunk = i * 256 + tid;
        int row = chunk >> 3, c8 = chunk & 7;
        int gcol = (row < 64) ? (n0 + row) : (DFF_DIM + n0 + (row - 64));
        bptr[i] = w1 + ((size_t)e * (2 * DFF_DIM) + gcol) * D_DIM + c8 * 8;
        wroff[i] = row * 128 + ((c8 * 16) ^ ((row & 7) << 4));
    }

    f32x4 rbA[4][2], rbB[4][2];
    f32x4 accg[4][2], accu[4][2];
#pragma unroll
    for (int m = 0; m < 4; ++m)
#pragma unroll
        for (int n = 0; n < 2; ++n) {
            accg[m][n] = (f32x4){0.f, 0.f, 0.f, 0.f};
            accu[m][n] = (f32x4){0.f, 0.f, 0.f, 0.f};
        }

#define MFMA_G1(bufA, bufB)                                               \
    _Pragma("unroll") for (int ks = 0; ks < 2; ++ks) {                    \
        const int inner = ks * 64 + lk * 16;                              \
        bf16x8 af[4], bg[2], bu[2];                                       \
        _Pragma("unroll") for (int m = 0; m < 4; ++m)                     \
            af[m] = lds_read8_swz(bufA, wm * 64 + m * 16 + lr, inner);    \
        _Pragma("unroll") for (int n = 0; n < 2; ++n) {                   \
            bg[n] = lds_read8_swz(bufB, wn * 32 + n * 16 + lr, inner);    \
            bu[n] = lds_read8_swz(bufB, 64 + wn * 32 + n * 16 + lr, inner); \
        }                                                                 \
        _Pragma("unroll") for (int m = 0; m < 4; ++m)                     \
            _Pragma("unroll") for (int n = 0; n < 2; ++n) {               \
                accg[m][n] = __builtin_amdgcn_mfma_f32_16x16x32_bf16(af[m], bg[n], accg[m][n], 0, 0, 0); \
                accu[m][n] = __builtin_amdgcn_mfma_f32_16x16x32_bf16(af[m], bu[n], accu[m][n], 0, 0, 0); \
            }                                                             \
    }

    const int KT = D_DIM / BK;   // 32 (even)
    // prologue: lB=tile0 (via rbA), rbB=tile1, lA[0]=A-tile0
    LOAD_RB(rbA, 0);
    GLL_A(0, lA[0]);
    CVT_WRITE(rbA, lB);
    LOAD_RB(rbB, BK);
    BAR_V8();                        // drain gll+ds_writes, keep rbB in flight

    for (int tt = 0; tt < KT; tt += 2) {
        {   // tile t = tt: lA[0], lB=tile t; rbB holds tile t+1 (loaded 2 steps ago)
            const int t = tt;
            if (t + 1 < KT) GLL_A((t + 1) * BK, lA[1]);
            const int kr = (t + 2 < KT ? t + 2 : KT - 1) * BK;
            LOAD_RB(rbA, kr);                     // rbA <- tile t+2
            PIN();
            MFMA_G1(lA[0], lB);
            BAR_LGKM();                           // lB reads done; vmem in flight
            if (t + 1 < KT) { CVT_WRITE(rbB, lB); }   // rbB landed long ago
            BAR_V8();                             // drain glls; keep rbA flying
        }
        {   // tile t = tt+1: lA[1], lB=tile t; rbA holds tile t+1
            const int t = tt + 1;
            if (t + 1 < KT) GLL_A((t + 1) * BK, lA[0]);
            const int kr = (t + 2 < KT ? t + 2 : KT - 1) * BK;
            LOAD_RB(rbB, kr);                     // rbB <- tile t+2
            PIN();
            MFMA_G1(lA[1], lB);
            BAR_LGKM();
            if (t + 1 < KT) { CVT_WRITE(rbA, lB); }
            BAR_V8();
        }
    }
#undef MFMA_G1

    // epilogue: h = silu(gate) * up  (C/D: col=lane&15, row=(lane>>4)*4+r)
#pragma unroll
    for (int m = 0; m < 4; ++m)
#pragma unroll
        for (int n = 0; n < 2; ++n)
#pragma unroll
            for (int r = 0; r < 4; ++r) {
                int rloc = wm * 64 + m * 16 + (lane >> 4) * 4 + r;
                if (rloc < mlen) {
                    int col = wn * 32 + n * 16 + lr;
                    float g = accg[m][n][r], u = accu[m][n][r];
                    float h = (g / (1.f + __expf(-g))) * u;
                    H[(size_t)(m0 + rloc) * DFF_DIM + n0 + col] = f2bf(h);
                }
            }
}

// ---------------- GEMM2: H(gll) @ w2(f32, 2-deep reg pipe), atomicAdd --------
__global__ __launch_bounds__(256, 3)
void gemm2_kernel(const u16* __restrict__ H, const float* __restrict__ w2,
                  const int* __restrict__ sched, const int* __restrict__ row_token,
                  const float* __restrict__ row_w, float* __restrict__ out) {
    __shared__ u16 lA[2][BM * BK];
    __shared__ u16 lB[BM * BK];

    DECODE_BLOCK();
    const int n0 = n0i * 128;

    const int tid  = threadIdx.x;
    const int lane = tid & 63;
    const int wave = tid >> 6;
    const int wm = wave >> 1, wn = wave & 1;
    const int lr = lane & 15, lk = lane >> 4;

    const u16* asrc[4];
    int aoff[4];
#pragma unroll
    for (int i = 0; i < 4; ++i) {
        int R = i * 32 + wave * 8 + (lane >> 3);
        int grow = m0 + R; if (grow > NROWS - 1) grow = NROWS - 1;
        asrc[i] = H + (size_t)grow * DFF_DIM + (size_t)(((lane & 7) ^ (R & 7)) * 8);
        aoff[i] = i * 2048 + wave * 512;
    }
    const float* bptr[4];
    int wroff[4];
#pragma unroll
    for (int i = 0; i < 4; ++i) {
        int chunk = i * 256 + tid;
        int row = chunk >> 3, c8 = chunk & 7;
        bptr[i] = w2 + ((size_t)e * D_DIM + (n0 + row)) * DFF_DIM + c8 * 8;
        wroff[i] = row * 128 + ((c8 * 16) ^ ((row & 7) << 4));
    }

    f32x4 rbA[4][2], rbB[4][2];
    f32x4 acc[4][4];
#pragma unroll
    for (int m = 0; m < 4; ++m)
#pragma unroll
        for (int n = 0; n < 4; ++n) acc[m][n] = (f32x4){0.f, 0.f, 0.f, 0.f};

#define MFMA_G2(bufA, bufB)                                               \
    _Pragma("unroll") for (int ks = 0; ks < 2; ++ks) {                    \
        const int inner = ks * 64 + lk * 16;                              \
        bf16x8 af[4], bfr[4];                                             \
        _Pragma("unroll") for (int m = 0; m < 4; ++m)                     \
            af[m] = lds_read8_swz(bufA, wm * 64 + m * 16 + lr, inner);    \
        _Pragma("unroll") for (int n = 0; n < 4; ++n)                     \
            bfr[n] = lds_read8_swz(bufB, wn * 64 + n * 16 + lr, inner);   \
        _Pragma("unroll") for (int m = 0; m < 4; ++m)                     \
            _Pragma("unroll") for (int n = 0; n < 4; ++n)                 \
                acc[m][n] = __builtin_amdgcn_mfma_f32_16x16x32_bf16(af[m], bfr[n], acc[m][n], 0, 0, 0); \
    }

    const int KT = DFF_DIM / BK;   // 16 (even)
    LOAD_RB(rbA, 0);
    GLL_A(0, lA[0]);
    CVT_WRITE(rbA, lB);
    LOAD_RB(rbB, BK);
    BAR_V8();

    for (int tt = 0; tt < KT; tt += 2) {
        {
            const int t = tt;
            if (t + 1 < KT) GLL_A((t + 1) * BK, lA[1]);
            const int kr = (t + 2 < KT ? t + 2 : KT - 1) * BK;
            LOAD_RB(rbA, kr);
            PIN();
            MFMA_G2(lA[0], lB);
            BAR_LGKM();
            if (t + 1 < KT) { CVT_WRITE(rbB, lB); }
            BAR_V8();
        }
        {
            const int t = tt + 1;
            if (t + 1 < KT) GLL_A((t + 1) * BK, lA[0]);
            const int kr = (t + 2 < KT ? t + 2 : KT - 1) * BK;
            LOAD_RB(rbB, kr);
            PIN();
            MFMA_G2(lA[1], lB);
            BAR_LGKM();
            if (t + 1 < KT) { CVT_WRITE(rbA, lB); }
            BAR_V8();
        }
    }
#undef MFMA_G2

#pragma unroll
    for (int m = 0; m < 4; ++m)
#pragma unroll
        for (int n = 0; n < 4; ++n)
#pragma unroll
            for (int r = 0; r < 4; ++r) {
                int rloc = wm * 64 + m * 16 + (lane >> 4) * 4 + r;
                if (rloc < mlen) {
                    int grow = m0 + rloc;
                    int tok  = row_token[grow];
                    float w  = row_w[grow];
                    int col  = wn * 64 + n * 16 + lr;
                    atomicAdd(&out[(size_t)tok * D_DIM + n0 + col], acc[m][n][r] * w);
                }
            }
}

extern "C" void kernel_launch(void* const* d_in, const int* in_sizes, int n_in,
                              void* d_out, int out_size, void* d_ws, size_t ws_size,
                              hipStream_t stream) {
    const float* X  = (const float*)d_in[0];
    const float* w1 = (const float*)d_in[1];
    const float* w2 = (const float*)d_in[2];
    const float* tw = (const float*)d_in[3];
    const int*   ti = (const int*)d_in[4];

    int*   sched     = (int*)d_ws;
    int*   row_token = (int*)((char*)d_ws + 512);
    float* row_w     = (float*)((char*)d_ws + 512 + 4 * NROWS);
    u16*   Xb        = (u16*)((char*)d_ws + XB_OFF);
    u16*   H         = (u16*)((char*)d_ws + H_OFF);

    prep_kernel<<<PREPX_BLKS + 1, 256, 0, stream>>>(X, Xb, (float*)d_out,
                                                    ti, tw, sched, row_token, row_w);
    gemm1_kernel<<<GRID_G, 256, 0, stream>>>(Xb, w1, sched, row_token, H);
    gemm2_kernel<<<GRID_G, 256, 0, stream>>>(H, w2, sched, row_token, row_w, (float*)d_out);
}

// Round 15
// 150.737 us; speedup vs baseline: 2.6503x; 2.6503x over previous
//
#include <hip/hip_runtime.h>
#include <hip/hip_bf16.h>
#include <stdint.h>

typedef __attribute__((ext_vector_type(4))) float f32x4;
typedef __attribute__((ext_vector_type(8))) short bf16x8;
typedef unsigned short u16;

#define T_TOK   2048
#define D_DIM   2048
#define DFF_DIM 1024
#define NEXP    8
#define TOPK    2
#define NROWS   (T_TOK * TOPK)   // 4096
#define BM      128
#define BK      64
#define MAX_MB  40
#define GRID_G  (16 * MAX_MB)    // 640 = 8 XCDs x 80

// ---- workspace layout (16.5 MB) ----
#define XB_OFF    65536
#define H_OFF     (XB_OFF + (size_t)T_TOK * D_DIM * 2)
#define X_T       ((size_t)T_TOK * D_DIM / 8)
#define PREPX_BLKS 512

__device__ __forceinline__ u16 f2bf(float f) {
    __hip_bfloat16 h = __float2bfloat16(f);
    return *reinterpret_cast<u16*>(&h);
}

__device__ __forceinline__ void cvt8_nt(const float* src, u16* dst) {
    f32x4 a = __builtin_nontemporal_load((const f32x4*)src);
    f32x4 b = __builtin_nontemporal_load(((const f32x4*)src) + 1);
    bf16x8 v;
#pragma unroll
    for (int j = 0; j < 4; ++j) { v[j] = (short)f2bf(a[j]); v[j + 4] = (short)f2bf(b[j]); }
    *(bf16x8*)dst = v;
}

__device__ __forceinline__ void gll16(const void* gsrc, const void* lds) {
    __builtin_amdgcn_global_load_lds(
        (const __attribute__((address_space(1))) uint32_t*)gsrc,
        (__attribute__((address_space(3))) uint32_t*)lds, 16, 0, 0);
}

// A tile: [128 rows][64 bf16 = 128B]; content XOR-swizzled by row (16B chunks)
__device__ __forceinline__ bf16x8 lds_read8_swz(const u16* base, int row, int inner) {
    int off = row * 128 + (inner ^ ((row & 7) << 4));
    return *(const bf16x8*)((const char*)base + off);
}

// B tile: [128 rows][64 f32 = 256B]; swizzle chunk16 ^= (row&15).
// Fragment = k-elems [ks*32+lk*8, +8) -> chunks c=ks*8+lk*2 and c+1.
// Converts f32 -> bf16x8 at read (compiler emits v_cvt_pk_bf16_f32).
__device__ __forceinline__ bf16x8 lds_readB(const float* base, int row, int ks, int lk) {
    const int c = ks * 8 + lk * 2;
    const int s = row & 15;
    const char* p = (const char*)base + row * 256;
    f32x4 lo = *(const f32x4*)(p + ((c ^ s) << 4));
    f32x4 hi = *(const f32x4*)(p + (((c + 1) ^ s) << 4));
    bf16x8 v;
#pragma unroll
    for (int j = 0; j < 4; ++j) { v[j] = (short)f2bf(lo[j]); v[j + 4] = (short)f2bf(hi[j]); }
    return v;
}

__device__ __forceinline__ void route_body(const int* topk_ids, const float* topk_w,
                                           int* sched, int* row_token, float* row_w,
                                           int* cnt, int* off, int* cur) {
    const int tid = threadIdx.x;
    if (tid < NEXP) cnt[tid] = 0;
    __syncthreads();
    for (int p = tid; p < NROWS; p += blockDim.x)
        atomicAdd(&cnt[topk_ids[p]], 1);
    __syncthreads();
    if (tid == 0) {
        int acc = 0, mb = 0;
        for (int e = 0; e < NEXP; ++e) {
            off[e] = acc;
            int c = cnt[e];
            for (int m0 = 0; m0 < c; m0 += BM) {
                sched[1 + 3 * mb] = e;
                sched[2 + 3 * mb] = acc + m0;
                sched[3 + 3 * mb] = (c - m0 < BM) ? (c - m0) : BM;
                ++mb;
            }
            acc += c;
        }
        sched[0] = mb;
    }
    if (tid < NEXP) cur[tid] = 0;
    __syncthreads();
    for (int p = tid; p < NROWS; p += blockDim.x) {
        int e = topk_ids[p];
        int slot = off[e] + atomicAdd(&cur[e], 1);
        row_token[slot] = p / TOPK;
        row_w[slot]     = topk_w[p];
    }
}

// ---------------- prep_small: X -> bf16 (NT); zero d_out; route --------------
__global__ void prep_kernel(const float* __restrict__ X,
                            u16* __restrict__ Xb, float* __restrict__ out,
                            const int* __restrict__ topk_ids,
                            const float* __restrict__ topk_w,
                            int* __restrict__ sched, int* __restrict__ row_token,
                            float* __restrict__ row_w) {
    __shared__ int cnt[NEXP], off[NEXP], cur[NEXP];
    if (blockIdx.x == PREPX_BLKS) {
        route_body(topk_ids, topk_w, sched, row_token, row_w, cnt, off, cur);
        return;
    }
    const size_t stride = (size_t)PREPX_BLKS * 256;
    for (size_t t = (size_t)blockIdx.x * 256 + threadIdx.x; t < X_T; t += stride) {
        cvt8_nt(X + t * 8, Xb + t * 8);
        f32x4 z = (f32x4){0.f, 0.f, 0.f, 0.f};
        *(f32x4*)(out + t * 8) = z;
        *(f32x4*)(out + t * 8 + 4) = z;
    }
}

// XCD map: blocks sharing a B-slice (same e,n0; different m0) land on ONE XCD
// -> the doubled f32 B traffic is served by that XCD's L2.
#define DECODE_BLOCK()                                                    \
    const int bid   = blockIdx.x;                                         \
    const int xcd   = bid & 7;                                            \
    const int local = bid >> 3;            /* 0..79 */                    \
    const int n0h   = local / MAX_MB;      /* 0..1  */                    \
    const int mb    = local - n0h * MAX_MB;                               \
    const int n0i   = xcd * 2 + n0h;       /* 0..15 */                    \
    if (mb >= sched[0]) return;                                           \
    const int e    = sched[1 + 3 * mb];                                   \
    const int m0   = sched[2 + 3 * mb];                                   \
    const int mlen = sched[3 + 3 * mb]

// ---------------- GEMM1: Xb(gll bf16) @ w1(gll f32, cvt-at-read) -------------
__global__ __launch_bounds__(256, 3)
void gemm1_kernel(const u16* __restrict__ Xb, const float* __restrict__ w1,
                  const int* __restrict__ sched, const int* __restrict__ row_token,
                  u16* __restrict__ H) {
    __shared__ u16   lA[BM * BK];    // 16KB bf16, gll (linear dest, pre-swz src)
    __shared__ float lBf[BM * BK];   // 32KB f32,  gll (linear dest, pre-swz src)

    DECODE_BLOCK();
    const int n0 = n0i * 64;

    const int tid  = threadIdx.x;
    const int lane = tid & 63;
    const int wave = tid >> 6;
    const int wm = wave >> 1, wn = wave & 1;
    const int lr = lane & 15, lk = lane >> 4;

    // A staging: 4 glls/thread, 16B each (bf16, 8 elems)
    const u16* asrc[4];
    int aoff[4];
#pragma unroll
    for (int i = 0; i < 4; ++i) {
        int R = i * 32 + wave * 8 + (lane >> 3);
        int grow = m0 + R; if (grow > NROWS - 1) grow = NROWS - 1;
        int tok = row_token[grow];
        asrc[i] = Xb + (size_t)tok * D_DIM + (size_t)(((lane & 7) ^ (R & 7)) * 8);
        aoff[i] = i * 2048 + wave * 512;
    }
    // B staging: 8 glls/thread, 16B each (f32, 4 elems); source pre-swizzled
    const float* bsrcf[8];
#pragma unroll
    for (int i = 0; i < 8; ++i) {
        int chunk = i * 256 + tid;
        int row = chunk >> 4, c16 = chunk & 15;
        int gcol = (row < 64) ? (n0 + row) : (DFF_DIM + n0 + (row - 64));
        bsrcf[i] = w1 + ((size_t)e * (2 * DFF_DIM) + gcol) * D_DIM
                      + (size_t)((c16 ^ (row & 15)) << 2);
    }

    f32x4 accg[4][2], accu[4][2];
#pragma unroll
    for (int m = 0; m < 4; ++m)
#pragma unroll
        for (int n = 0; n < 2; ++n) {
            accg[m][n] = (f32x4){0.f, 0.f, 0.f, 0.f};
            accu[m][n] = (f32x4){0.f, 0.f, 0.f, 0.f};
        }

    const int KT = D_DIM / BK;   // 32
    for (int kt = 0; kt < KT; ++kt) {
        const int k0 = kt * BK;
#pragma unroll
        for (int i = 0; i < 4; ++i) gll16(asrc[i] + k0, &lA[aoff[i]]);
#pragma unroll
        for (int i = 0; i < 8; ++i)
            gll16(bsrcf[i] + k0, &lBf[i * 1024 + wave * 256]);
        __syncthreads();   // drains glls
#pragma unroll
        for (int ks = 0; ks < 2; ++ks) {
            const int inner = ks * 64 + lk * 16;
            bf16x8 af[4], bg[2], bu[2];
#pragma unroll
            for (int m = 0; m < 4; ++m)
                af[m] = lds_read8_swz(lA, wm * 64 + m * 16 + lr, inner);
#pragma unroll
            for (int n = 0; n < 2; ++n) {
                bg[n] = lds_readB(lBf, wn * 32 + n * 16 + lr, ks, lk);
                bu[n] = lds_readB(lBf, 64 + wn * 32 + n * 16 + lr, ks, lk);
            }
#pragma unroll
            for (int m = 0; m < 4; ++m)
#pragma unroll
                for (int n = 0; n < 2; ++n) {
                    accg[m][n] = __builtin_amdgcn_mfma_f32_16x16x32_bf16(af[m], bg[n], accg[m][n], 0, 0, 0);
                    accu[m][n] = __builtin_amdgcn_mfma_f32_16x16x32_bf16(af[m], bu[n], accu[m][n], 0, 0, 0);
                }
        }
        __syncthreads();   // reads done before next overwrite
    }

    // epilogue: h = silu(gate) * up  (C/D: col=lane&15, row=(lane>>4)*4+r)
#pragma unroll
    for (int m = 0; m < 4; ++m)
#pragma unroll
        for (int n = 0; n < 2; ++n)
#pragma unroll
            for (int r = 0; r < 4; ++r) {
                int rloc = wm * 64 + m * 16 + (lane >> 4) * 4 + r;
                if (rloc < mlen) {
                    int col = wn * 32 + n * 16 + lr;
                    float g = accg[m][n][r], u = accu[m][n][r];
                    float h = (g / (1.f + __expf(-g))) * u;
                    H[(size_t)(m0 + rloc) * DFF_DIM + n0 + col] = f2bf(h);
                }
            }
}

// ---------------- GEMM2: H(gll bf16) @ w2(gll f32, cvt-at-read), atomicAdd ---
__global__ __launch_bounds__(256, 3)
void gemm2_kernel(const u16* __restrict__ H, const float* __restrict__ w2,
                  const int* __restrict__ sched, const int* __restrict__ row_token,
                  const float* __restrict__ row_w, float* __restrict__ out) {
    __shared__ u16   lA[BM * BK];    // 16KB
    __shared__ float lBf[BM * BK];   // 32KB

    DECODE_BLOCK();
    const int n0 = n0i * 128;

    const int tid  = threadIdx.x;
    const int lane = tid & 63;
    const int wave = tid >> 6;
    const int wm = wave >> 1, wn = wave & 1;
    const int lr = lane & 15, lk = lane >> 4;

    const u16* asrc[4];
    int aoff[4];
#pragma unroll
    for (int i = 0; i < 4; ++i) {
        int R = i * 32 + wave * 8 + (lane >> 3);
        int grow = m0 + R; if (grow > NROWS - 1) grow = NROWS - 1;
        asrc[i] = H + (size_t)grow * DFF_DIM + (size_t)(((lane & 7) ^ (R & 7)) * 8);
        aoff[i] = i * 2048 + wave * 512;
    }
    const float* bsrcf[8];
#pragma unroll
    for (int i = 0; i < 8; ++i) {
        int chunk = i * 256 + tid;
        int row = chunk >> 4, c16 = chunk & 15;
        bsrcf[i] = w2 + ((size_t)e * D_DIM + (n0 + row)) * DFF_DIM
                      + (size_t)((c16 ^ (row & 15)) << 2);
    }

    f32x4 acc[4][4];
#pragma unroll
    for (int m = 0; m < 4; ++m)
#pragma unroll
        for (int n = 0; n < 4; ++n) acc[m][n] = (f32x4){0.f, 0.f, 0.f, 0.f};

    const int KT = DFF_DIM / BK;   // 16
    for (int kt = 0; kt < KT; ++kt) {
        const int k0 = kt * BK;
#pragma unroll
        for (int i = 0; i < 4; ++i) gll16(asrc[i] + k0, &lA[aoff[i]]);
#pragma unroll
        for (int i = 0; i < 8; ++i)
            gll16(bsrcf[i] + k0, &lBf[i * 1024 + wave * 256]);
        __syncthreads();
#pragma unroll
        for (int ks = 0; ks < 2; ++ks) {
            const int inner = ks * 64 + lk * 16;
            bf16x8 af[4], bfr[4];
#pragma unroll
            for (int m = 0; m < 4; ++m)
                af[m] = lds_read8_swz(lA, wm * 64 + m * 16 + lr, inner);
#pragma unroll
            for (int n = 0; n < 4; ++n)
                bfr[n] = lds_readB(lBf, wn * 64 + n * 16 + lr, ks, lk);
#pragma unroll
            for (int m = 0; m < 4; ++m)
#pragma unroll
                for (int n = 0; n < 4; ++n)
                    acc[m][n] = __builtin_amdgcn_mfma_f32_16x16x32_bf16(af[m], bfr[n], acc[m][n], 0, 0, 0);
        }
        __syncthreads();
    }

#pragma unroll
    for (int m = 0; m < 4; ++m)
#pragma unroll
        for (int n = 0; n < 4; ++n)
#pragma unroll
            for (int r = 0; r < 4; ++r) {
                int rloc = wm * 64 + m * 16 + (lane >> 4) * 4 + r;
                if (rloc < mlen) {
                    int grow = m0 + rloc;
                    int tok  = row_token[grow];
                    float w  = row_w[grow];
                    int col  = wn * 64 + n * 16 + lr;
                    atomicAdd(&out[(size_t)tok * D_DIM + n0 + col], acc[m][n][r] * w);
                }
            }
}

extern "C" void kernel_launch(void* const* d_in, const int* in_sizes, int n_in,
                              void* d_out, int out_size, void* d_ws, size_t ws_size,
                              hipStream_t stream) {
    const float* X  = (const float*)d_in[0];
    const float* w1 = (const float*)d_in[1];
    const float* w2 = (const float*)d_in[2];
    const float* tw = (const float*)d_in[3];
    const int*   ti = (const int*)d_in[4];

    int*   sched     = (int*)d_ws;
    int*   row_token = (int*)((char*)d_ws + 512);
    float* row_w     = (float*)((char*)d_ws + 512 + 4 * NROWS);
    u16*   Xb        = (u16*)((char*)d_ws + XB_OFF);
    u16*   H         = (u16*)((char*)d_ws + H_OFF);

    prep_kernel<<<PREPX_BLKS + 1, 256, 0, stream>>>(X, Xb, (float*)d_out,
                                                    ti, tw, sched, row_token, row_w);
    gemm1_kernel<<<GRID_G, 256, 0, stream>>>(Xb, w1, sched, row_token, H);
    gemm2_kernel<<<GRID_G, 256, 0, stream>>>(H, w2, sched, row_token, row_w, (float*)d_out);
}